// Round 1
// baseline (54312.537 us; speedup 1.0000x reference)
//
#include <hip/hip_runtime.h>
#include <math.h>

// ---------------------------------------------------------------------------
// LSTMModel: fp32 correctness-first implementation.
//   N=128 T=256 QN=16 QD=32 8 cat feats (100 ea) LD=32 -> IN_DIM=768
//   H=1024, L=2, OUT=2
// Per step: gates = [h | x] @ W + b ; 4x LayerNorm over H; gate math;
//   x_next = og*tanh(c) + gn ; last layer -> logits @ fcW -> softmax.
// ---------------------------------------------------------------------------

#define N_   128
#define T_   256
#define QN_  16
#define INX  24      // x last dim = 16 numeric + 8 categorical
#define H_   1024
#define G4   4096    // 4*H
#define FDIM 768     // IN_DIM
#define EPS_ 1e-5f

__device__ __forceinline__ float sigmoidf_(float v) { return 1.0f / (1.0f + expf(-v)); }

// ---- BatchNorm stats over the (N*T, 16) numeric block --------------------
__global__ __launch_bounds__(256) void bn_stats_k(const float* __restrict__ x,
    const float* __restrict__ gamma, const float* __restrict__ beta,
    float* __restrict__ scale, float* __restrict__ shift) {
  int q = blockIdx.x;          // 0..15
  int tid = threadIdx.x;
  float s = 0.f, s2 = 0.f;
  for (int r = tid; r < N_ * T_; r += 256) {
    float v = x[(size_t)r * INX + q];
    s += v; s2 += v * v;
  }
  for (int off = 32; off; off >>= 1) { s += __shfl_down(s, off); s2 += __shfl_down(s2, off); }
  __shared__ float red[2][4];
  int w = tid >> 6;
  if ((tid & 63) == 0) { red[0][w] = s; red[1][w] = s2; }
  __syncthreads();
  if (tid == 0) {
    float S = 0.f, S2 = 0.f;
    for (int i = 0; i < 4; ++i) { S += red[0][i]; S2 += red[1][i]; }
    float m   = S  / (float)(N_ * T_);
    float var = S2 / (float)(N_ * T_) - m * m;   // population var
    float rs  = rsqrtf(var + EPS_);
    scale[q] = rs * gamma[q];
    shift[q] = beta[q] - m * rs * gamma[q];
  }
}

// ---- Per-step feature build: feats_t (128 x 768) -------------------------
__global__ __launch_bounds__(256) void feats_k(const float* __restrict__ x, int t,
    const float* __restrict__ scale, const float* __restrict__ shift,
    const float* __restrict__ QnV, const float* __restrict__ QlV,
    float* __restrict__ fbuf) {
  int n = blockIdx.x;
  const float* xr = x + ((size_t)n * T_ + t) * INX;
  for (int f = threadIdx.x; f < FDIM; f += 256) {
    int d = f & 31;
    float v;
    if (f < 512) {                       // qn_emb: normalized qn * QnV
      int q = f >> 5;
      v = (xr[q] * scale[q] + shift[q]) * QnV[q * 32 + d];
    } else {                             // ql_emb: table lookup with offsets
      int cg = (f - 512) >> 5;
      int idx = (int)xr[QN_ + cg] + cg * 100;
      v = QlV[idx * 32 + d];
    }
    fbuf[n * FDIM + f] = v;
  }
}

// ---- Gates GEMM: out(128x4096) = [A1|A2](128x(K1+K2)) @ W + bias ---------
#define BM 32
#define BN 64
#define BK 16
__global__ __launch_bounds__(256) void gemm_k(
    const float* __restrict__ A1, int K1,
    const float* __restrict__ A2, int K2,
    const float* __restrict__ W, const float* __restrict__ bias,
    float* __restrict__ out) {
  __shared__ float As[BK][BM];
  __shared__ float Bs[BK][BN];
  int tid  = threadIdx.x;
  int col0 = blockIdx.x * BN;
  int row0 = blockIdx.y * BM;
  int a_k = tid & 15, a_m = tid >> 4;   // A loader: rows a_m, a_m+16
  int b_j = tid & 63, b_k = tid >> 6;   // B loader: k = b_k + 4*i
  int tm  = tid >> 4, tn = tid & 15;    // compute: rows tm*2+{0,1}, cols tn*4+{0..3}
  float acc[2][4] = {};
  int K = K1 + K2;
  for (int k0 = 0; k0 < K; k0 += BK) {
    const float* A; int kk, lda;
    if (k0 < K1) { A = A1; kk = k0;      lda = K1; }
    else         { A = A2; kk = k0 - K1; lda = K2; }
    As[a_k][a_m]      = A[(size_t)(row0 + a_m)      * lda + kk + a_k];
    As[a_k][a_m + 16] = A[(size_t)(row0 + a_m + 16) * lda + kk + a_k];
#pragma unroll
    for (int i = 0; i < 4; ++i) {
      int k = b_k + 4 * i;
      Bs[k][b_j] = W[(size_t)(k0 + k) * G4 + col0 + b_j];
    }
    __syncthreads();
#pragma unroll
    for (int k = 0; k < BK; ++k) {
      float a0 = As[k][tm * 2], a1 = As[k][tm * 2 + 1];
      float b0 = Bs[k][tn * 4], b1 = Bs[k][tn * 4 + 1];
      float b2 = Bs[k][tn * 4 + 2], b3 = Bs[k][tn * 4 + 3];
      acc[0][0] += a0 * b0; acc[0][1] += a0 * b1; acc[0][2] += a0 * b2; acc[0][3] += a0 * b3;
      acc[1][0] += a1 * b0; acc[1][1] += a1 * b1; acc[1][2] += a1 * b2; acc[1][3] += a1 * b3;
    }
    __syncthreads();
  }
#pragma unroll
  for (int i = 0; i < 2; ++i) {
    int m = row0 + tm * 2 + i;
#pragma unroll
    for (int j = 0; j < 4; ++j) {
      int cc = col0 + tn * 4 + j;
      out[(size_t)m * G4 + cc] = acc[i][j] + bias[cc];
    }
  }
}

// ---- Cell: 4x LayerNorm + gate math + state update (+ logits/softmax) ----
__global__ __launch_bounds__(256) void cell_k(const float* __restrict__ gates,
    float* __restrict__ h, float* __restrict__ c,
    const float* __restrict__ lng, const float* __restrict__ lnb,   // (4,1024)
    const float* __restrict__ fcW, const float* __restrict__ fcb,
    float* __restrict__ out, int t, int do_logits) {
  int n = blockIdx.x, tid = threadIdx.x;
  __shared__ float srow[G4];
  __shared__ float red[8][4];
  __shared__ float stat[8];    // [0..3]=mean, [4..7]=rstd
  const float* grow = gates + (size_t)n * G4;
  for (int i = tid; i < G4; i += 256) srow[i] = grow[i];
  __syncthreads();
  float s[4], s2[4];
#pragma unroll
  for (int g = 0; g < 4; ++g) { s[g] = 0.f; s2[g] = 0.f; }
  for (int i = tid; i < H_; i += 256)
#pragma unroll
    for (int g = 0; g < 4; ++g) { float v = srow[g * H_ + i]; s[g] += v; s2[g] += v * v; }
  for (int off = 32; off; off >>= 1)
#pragma unroll
    for (int g = 0; g < 4; ++g) { s[g] += __shfl_down(s[g], off); s2[g] += __shfl_down(s2[g], off); }
  int w = tid >> 6;
  if ((tid & 63) == 0)
#pragma unroll
    for (int g = 0; g < 4; ++g) { red[g][w] = s[g]; red[4 + g][w] = s2[g]; }
  __syncthreads();
  if (tid < 4) {
    int g = tid;
    float S = 0.f, S2 = 0.f;
    for (int i = 0; i < 4; ++i) { S += red[g][i]; S2 += red[4 + g][i]; }
    float m   = S / (float)H_;
    float var = S2 / (float)H_ - m * m;       // population var
    stat[g]     = m;
    stat[4 + g] = rsqrtf(var + EPS_);
  }
  __syncthreads();
  float l0 = 0.f, l1 = 0.f;
  for (int i = tid; i < H_; i += 256) {
    float ig = (srow[i]          - stat[0]) * stat[4] * lng[i]           + lnb[i];
    float fg = (srow[H_ + i]     - stat[1]) * stat[5] * lng[H_ + i]      + lnb[H_ + i];
    float gn = (srow[2 * H_ + i] - stat[2]) * stat[6] * lng[2 * H_ + i]  + lnb[2 * H_ + i];
    float og = (srow[3 * H_ + i] - stat[3]) * stat[7] * lng[3 * H_ + i]  + lnb[3 * H_ + i];
    ig = sigmoidf_(ig); fg = sigmoidf_(fg); og = sigmoidf_(og);
    float cn = c[(size_t)n * H_ + i] * fg + ig * tanhf(gn);
    float xn = og * tanhf(cn) + gn;
    c[(size_t)n * H_ + i] = cn;
    h[(size_t)n * H_ + i] = xn;
    if (do_logits) { l0 += xn * fcW[i * 2]; l1 += xn * fcW[i * 2 + 1]; }
  }
  if (do_logits) {
    for (int off = 32; off; off >>= 1) { l0 += __shfl_down(l0, off); l1 += __shfl_down(l1, off); }
    if ((tid & 63) == 0) { red[0][w] = l0; red[1][w] = l1; }
    __syncthreads();
    if (tid == 0) {
      float L0 = fcb[0], L1 = fcb[1];
      for (int i = 0; i < 4; ++i) { L0 += red[0][i]; L1 += red[1][i]; }
      float mx = fmaxf(L0, L1);
      float e0 = expf(L0 - mx), e1 = expf(L1 - mx);
      float inv = 1.f / (e0 + e1);
      float* op = out + ((size_t)n * T_ + t) * 2;
      op[0] = e0 * inv; op[1] = e1 * inv;
    }
  }
}

// ---------------------------------------------------------------------------
extern "C" void kernel_launch(void* const* d_in, const int* in_sizes, int n_in,
                              void* d_out, int out_size, void* d_ws, size_t ws_size,
                              hipStream_t stream) {
  const float* x   = (const float*)d_in[0];
  const float* QnV = (const float*)d_in[1];
  const float* QlV = (const float*)d_in[2];
  const float* bng = (const float*)d_in[3];
  const float* bnb = (const float*)d_in[4];
  const float* W0  = (const float*)d_in[5];
  const float* b0  = (const float*)d_in[6];
  const float* W1  = (const float*)d_in[7];
  const float* b1  = (const float*)d_in[8];
  const float* lng = (const float*)d_in[9];   // (2,4,1024)
  const float* lnb = (const float*)d_in[10];
  const float* fcW = (const float*)d_in[11];  // (1024,2)
  const float* fcb = (const float*)d_in[12];
  float* out = (float*)d_out;

  float* base  = (float*)d_ws;
  float* scale = base;                 // 16
  float* shift = base + 16;            // 16
  float* h0    = base + 32;            // 128*1024
  float* h1    = h0 + N_ * H_;
  float* c0    = h1 + N_ * H_;
  float* c1    = c0 + N_ * H_;
  float* gates = c1 + N_ * H_;         // 128*4096
  float* fbuf  = gates + (size_t)N_ * G4;  // 128*768

  // zero initial h/c (h0,h1,c0,c1 are contiguous)
  hipMemsetAsync(h0, 0, (size_t)4 * N_ * H_ * sizeof(float), stream);
  bn_stats_k<<<QN_, 256, 0, stream>>>(x, bng, bnb, scale, shift);

  dim3 ggrid(G4 / BN, N_ / BM);
  for (int t = 0; t < T_; ++t) {
    feats_k<<<N_, 256, 0, stream>>>(x, t, scale, shift, QnV, QlV, fbuf);
    // layer 0: inp = [h0 | feats_t]
    gemm_k<<<ggrid, 256, 0, stream>>>(h0, H_, fbuf, FDIM, W0, b0, gates);
    cell_k<<<N_, 256, 0, stream>>>(gates, h0, c0, lng, lnb,
                                   nullptr, nullptr, nullptr, t, 0);
    // layer 1: inp = [h1 | h0_new]
    gemm_k<<<ggrid, 256, 0, stream>>>(h1, H_, h0, H_, W1, b1, gates);
    cell_k<<<N_, 256, 0, stream>>>(gates, h1, c1, lng + 4 * H_, lnb + 4 * H_,
                                   fcW, fcb, out, t, 1);
  }
}

// Round 2
// 10245.199 us; speedup vs baseline: 5.3013x; 5.3013x over previous
//
#include <hip/hip_runtime.h>
#include <math.h>

// ---------------------------------------------------------------------------
// LSTMModel, round 2: bf16 MFMA gates GEMM (split-K=2), weights pre-converted
// to bf16 transposed once per call; cell kernel sums split-K partials + bias,
// writes h as bf16, and fuses next-step feature building.
//   N=128 T=256 H=1024 L=2, IN_DIM=768, gates=4096
// ---------------------------------------------------------------------------

#define N_   128
#define T_   256
#define QN_  16
#define INX  24
#define H_   1024
#define G4   4096
#define FDIM 768
#define EPS_ 1e-5f

typedef unsigned short u16;
typedef __attribute__((ext_vector_type(8))) short bf16x8;
typedef __attribute__((ext_vector_type(4))) float f32x4;

__device__ __forceinline__ float sigmoidf_(float v) { return 1.0f / (1.0f + expf(-v)); }

__device__ __forceinline__ u16 f2bf(float f) {
  unsigned u = __float_as_uint(f);
  u += 0x7fffu + ((u >> 16) & 1u);           // round-to-nearest-even
  return (u16)(u >> 16);
}

__device__ __forceinline__ void gload16(const void* g, void* l) {
  __builtin_amdgcn_global_load_lds((const __attribute__((address_space(1))) void*)g,
                                   (__attribute__((address_space(3))) void*)l, 16, 0, 0);
}

// ---- BatchNorm stats over the (N*T, 16) numeric block --------------------
__global__ __launch_bounds__(256) void bn_stats_k(const float* __restrict__ x,
    const float* __restrict__ gamma, const float* __restrict__ beta,
    float* __restrict__ scale, float* __restrict__ shift) {
  int q = blockIdx.x;
  int tid = threadIdx.x;
  float s = 0.f, s2 = 0.f;
  for (int r = tid; r < N_ * T_; r += 256) {
    float v = x[(size_t)r * INX + q];
    s += v; s2 += v * v;
  }
  for (int off = 32; off; off >>= 1) { s += __shfl_down(s, off); s2 += __shfl_down(s2, off); }
  __shared__ float red[2][4];
  int w = tid >> 6;
  if ((tid & 63) == 0) { red[0][w] = s; red[1][w] = s2; }
  __syncthreads();
  if (tid == 0) {
    float S = 0.f, S2 = 0.f;
    for (int i = 0; i < 4; ++i) { S += red[0][i]; S2 += red[1][i]; }
    float m   = S  / (float)(N_ * T_);
    float var = S2 / (float)(N_ * T_) - m * m;
    float rs  = rsqrtf(var + EPS_);
    scale[q] = rs * gamma[q];
    shift[q] = beta[q] - m * rs * gamma[q];
  }
}

// ---- Weight convert + transpose: W[k][n] fp32 -> Wt[n][k] bf16 -----------
__global__ __launch_bounds__(256) void wconv_k(const float* __restrict__ W,
                                               u16* __restrict__ Wt, int K) {
  __shared__ u16 L[64][72];
  int tid = threadIdx.x;
  int k0 = blockIdx.x * 64, n0 = blockIdx.y * 64;
#pragma unroll
  for (int it = 0; it < 16; ++it) {
    int e = it * 256 + tid;
    int r = e >> 6, c = e & 63;
    L[r][c] = f2bf(W[(size_t)(k0 + r) * G4 + n0 + c]);
  }
  __syncthreads();
  int n = tid >> 2, kc = (tid & 3) << 4;
  u16* dst = Wt + (size_t)(n0 + n) * K + k0 + kc;
#pragma unroll
  for (int j = 0; j < 16; ++j) dst[j] = L[kc + j][n];
}

// ---- Feature build for one step t (bf16 output) --------------------------
__device__ __forceinline__ void build_feats_row(const float* __restrict__ xr,
    const float* __restrict__ scale, const float* __restrict__ shift,
    const float* __restrict__ QnV, const float* __restrict__ QlV,
    u16* __restrict__ frow, int tid) {
  for (int f = tid; f < FDIM; f += 256) {
    int d = f & 31;
    float v;
    if (f < 512) {
      int q = f >> 5;
      v = (xr[q] * scale[q] + shift[q]) * QnV[q * 32 + d];
    } else {
      int cg = (f - 512) >> 5;
      int idx = (int)xr[QN_ + cg] + cg * 100;
      v = QlV[idx * 32 + d];
    }
    frow[f] = f2bf(v);
  }
}

__global__ __launch_bounds__(256) void feats_k(const float* __restrict__ x, int t,
    const float* __restrict__ scale, const float* __restrict__ shift,
    const float* __restrict__ QnV, const float* __restrict__ QlV,
    u16* __restrict__ fbuf) {
  int n = blockIdx.x;
  build_feats_row(x + ((size_t)n * T_ + t) * INX, scale, shift, QnV, QlV,
                  fbuf + (size_t)n * FDIM, threadIdx.x);
}

// ---- MFMA gates GEMM: partial[z](128x4096) = [A1|A2] @ Wt^T --------------
// A1,A2 row-major bf16 (lda=K1/K2); Bt[n][k] bf16 (n-major, stride Ktot).
// Block tile 64x64, BK=64, 4 waves (2x2), wave tile 32x32 (2x2 MFMA frags).
// LDS layout: 16B chunks XOR-swizzled: chunk at (row m, pos c) holds source
// chunk (c ^ (m&7)) -> conflict-free ds_read_b128 (guide G4/m173).
__global__ __launch_bounds__(256) void mfma_gemm_k(
    const u16* __restrict__ A1, int K1,
    const u16* __restrict__ A2, int K2,
    const u16* __restrict__ Bt, int Ktot, int Khalf,
    float* __restrict__ outp) {
  __shared__ u16 As[64 * 64];
  __shared__ u16 Bs[64 * 64];
  int tid  = threadIdx.x;
  int col0 = blockIdx.x * 64;
  int row0 = blockIdx.y * 64;
  int kb   = blockIdx.z * Khalf;
  float* op = outp + (size_t)blockIdx.z * ((size_t)N_ * G4);

  int lane = tid & 63, wave = tid >> 6;
  int wm = wave >> 1, wn = wave & 1;
  int lr = lane & 15, g = lane >> 4;

  int aoff[2][2], boff[2][2];
#pragma unroll
  for (int f = 0; f < 2; ++f) {
    int ma = wm * 32 + f * 16 + lr;
    int nb = wn * 32 + f * 16 + lr;
#pragma unroll
    for (int ks = 0; ks < 2; ++ks) {
      aoff[f][ks] = ma * 64 + (((ks * 4 + g) ^ (ma & 7)) << 3);
      boff[f][ks] = nb * 64 + (((ks * 4 + g) ^ (nb & 7)) << 3);
    }
  }

  f32x4 zero = {0.f, 0.f, 0.f, 0.f};
  f32x4 acc[2][2];
#pragma unroll
  for (int i = 0; i < 2; ++i)
#pragma unroll
    for (int j = 0; j < 2; ++j) acc[i][j] = zero;

  for (int kt = kb; kt < kb + Khalf; kt += 64) {
#pragma unroll
    for (int is = 0; is < 2; ++is) {
      int s = is * 256 + tid;            // 16B slot id, 0..511
      int m = s >> 3, c = s & 7;
      int ke = kt + ((c ^ (m & 7)) << 3);  // element index of this chunk
      const u16* ga = (ke < K1) ? (A1 + (size_t)(row0 + m) * K1 + ke)
                                : (A2 + (size_t)(row0 + m) * K2 + (ke - K1));
      gload16(ga, &As[s * 8]);
      const u16* gb = Bt + (size_t)(col0 + m) * Ktot + ke;
      gload16(gb, &Bs[s * 8]);
    }
    __syncthreads();                     // drains vmcnt, LDS visible
    bf16x8 af[2][2], bfr[2][2];
#pragma unroll
    for (int f = 0; f < 2; ++f)
#pragma unroll
      for (int ks = 0; ks < 2; ++ks) {
        af[f][ks]  = *(const bf16x8*)&As[aoff[f][ks]];
        bfr[f][ks] = *(const bf16x8*)&Bs[boff[f][ks]];
      }
#pragma unroll
    for (int fm = 0; fm < 2; ++fm)
#pragma unroll
      for (int fn = 0; fn < 2; ++fn) {
        acc[fm][fn] = __builtin_amdgcn_mfma_f32_16x16x32_bf16(af[fm][0], bfr[fn][0], acc[fm][fn], 0, 0, 0);
        acc[fm][fn] = __builtin_amdgcn_mfma_f32_16x16x32_bf16(af[fm][1], bfr[fn][1], acc[fm][fn], 0, 0, 0);
      }
    __syncthreads();
  }
#pragma unroll
  for (int fm = 0; fm < 2; ++fm) {
    int rbase = row0 + wm * 32 + fm * 16 + g * 4;
#pragma unroll
    for (int fn = 0; fn < 2; ++fn) {
      int cc = col0 + wn * 32 + fn * 16 + lr;
#pragma unroll
      for (int r = 0; r < 4; ++r)
        op[(size_t)(rbase + r) * G4 + cc] = acc[fm][fn][r];
    }
  }
}

// ---- Cell: sum split-K partials + bias, 4x LayerNorm, gate math, update --
__global__ __launch_bounds__(256) void cell_k(
    const float* __restrict__ p0, const float* __restrict__ p1,
    const float* __restrict__ bias,
    u16* __restrict__ hb, float* __restrict__ c,
    const float* __restrict__ lng, const float* __restrict__ lnb,
    const float* __restrict__ fcW, const float* __restrict__ fcb,
    float* __restrict__ out, int t, int do_logits,
    const float* __restrict__ x, const float* __restrict__ scale,
    const float* __restrict__ shift, const float* __restrict__ QnV,
    const float* __restrict__ QlV, u16* __restrict__ fbuf, int build_t) {
  int n = blockIdx.x, tid = threadIdx.x;
  __shared__ float srow[G4];
  __shared__ float red[8][4];
  __shared__ float stat[8];
  size_t base = (size_t)n * G4;
  for (int i = tid; i < G4; i += 256) srow[i] = p0[base + i] + p1[base + i] + bias[i];
  __syncthreads();
  float s[4], s2[4];
#pragma unroll
  for (int g = 0; g < 4; ++g) { s[g] = 0.f; s2[g] = 0.f; }
  for (int i = tid; i < H_; i += 256)
#pragma unroll
    for (int g = 0; g < 4; ++g) { float v = srow[g * H_ + i]; s[g] += v; s2[g] += v * v; }
  for (int off = 32; off; off >>= 1)
#pragma unroll
    for (int g = 0; g < 4; ++g) { s[g] += __shfl_down(s[g], off); s2[g] += __shfl_down(s2[g], off); }
  int w = tid >> 6;
  if ((tid & 63) == 0)
#pragma unroll
    for (int g = 0; g < 4; ++g) { red[g][w] = s[g]; red[4 + g][w] = s2[g]; }
  __syncthreads();
  if (tid < 4) {
    int g = tid;
    float S = 0.f, S2 = 0.f;
    for (int i = 0; i < 4; ++i) { S += red[g][i]; S2 += red[4 + g][i]; }
    float m   = S / (float)H_;
    float var = S2 / (float)H_ - m * m;
    stat[g]     = m;
    stat[4 + g] = rsqrtf(var + EPS_);
  }
  __syncthreads();
  float l0 = 0.f, l1 = 0.f;
  for (int i = tid; i < H_; i += 256) {
    float ig = (srow[i]          - stat[0]) * stat[4] * lng[i]          + lnb[i];
    float fg = (srow[H_ + i]     - stat[1]) * stat[5] * lng[H_ + i]     + lnb[H_ + i];
    float gn = (srow[2 * H_ + i] - stat[2]) * stat[6] * lng[2 * H_ + i] + lnb[2 * H_ + i];
    float og = (srow[3 * H_ + i] - stat[3]) * stat[7] * lng[3 * H_ + i] + lnb[3 * H_ + i];
    ig = sigmoidf_(ig); fg = sigmoidf_(fg); og = sigmoidf_(og);
    float cn = c[(size_t)n * H_ + i] * fg + ig * tanhf(gn);
    float xn = og * tanhf(cn) + gn;
    c[(size_t)n * H_ + i] = cn;
    hb[(size_t)n * H_ + i] = f2bf(xn);
    if (do_logits) { l0 += xn * fcW[i * 2]; l1 += xn * fcW[i * 2 + 1]; }
  }
  if (do_logits) {
    for (int off = 32; off; off >>= 1) { l0 += __shfl_down(l0, off); l1 += __shfl_down(l1, off); }
    if ((tid & 63) == 0) { red[0][w] = l0; red[1][w] = l1; }
    __syncthreads();
    if (tid == 0) {
      float L0 = fcb[0], L1 = fcb[1];
      for (int i = 0; i < 4; ++i) { L0 += red[0][i]; L1 += red[1][i]; }
      float mx = fmaxf(L0, L1);
      float e0 = expf(L0 - mx), e1 = expf(L1 - mx);
      float inv = 1.f / (e0 + e1);
      float* op = out + ((size_t)n * T_ + t) * 2;
      op[0] = e0 * inv; op[1] = e1 * inv;
    }
  }
  if (build_t >= 0) {
    build_feats_row(x + ((size_t)n * T_ + build_t) * INX, scale, shift, QnV, QlV,
                    fbuf + (size_t)n * FDIM, tid);
  }
}

// ---------------------------------------------------------------------------
extern "C" void kernel_launch(void* const* d_in, const int* in_sizes, int n_in,
                              void* d_out, int out_size, void* d_ws, size_t ws_size,
                              hipStream_t stream) {
  const float* x   = (const float*)d_in[0];
  const float* QnV = (const float*)d_in[1];
  const float* QlV = (const float*)d_in[2];
  const float* bng = (const float*)d_in[3];
  const float* bnb = (const float*)d_in[4];
  const float* W0  = (const float*)d_in[5];
  const float* b0  = (const float*)d_in[6];
  const float* W1  = (const float*)d_in[7];
  const float* b1  = (const float*)d_in[8];
  const float* lng = (const float*)d_in[9];
  const float* lnb = (const float*)d_in[10];
  const float* fcW = (const float*)d_in[11];
  const float* fcb = (const float*)d_in[12];
  float* out = (float*)d_out;

  float* fbase = (float*)d_ws;
  float* scale = fbase;                       // 64 (16 used)
  float* shift = fbase + 64;                  // 64
  float* c0    = fbase + 128;                 // 128*1024
  float* c1    = c0 + (size_t)N_ * H_;
  float* part  = c1 + (size_t)N_ * H_;        // 2 * 128*4096
  u16* h0b   = (u16*)(part + 2 * (size_t)N_ * G4);
  u16* h1b   = h0b + (size_t)N_ * H_;
  u16* fbufb = h1b + (size_t)N_ * H_;         // 128*768
  u16* Wt0   = fbufb + (size_t)N_ * FDIM;     // 4096*1792
  u16* Wt1   = Wt0 + (size_t)G4 * 1792;       // 4096*2048

  // zero c (fp32) and h (bf16, zero bits)
  hipMemsetAsync(c0, 0, 2 * (size_t)N_ * H_ * sizeof(float), stream);
  hipMemsetAsync(h0b, 0, 2 * (size_t)N_ * H_ * sizeof(u16), stream);

  // one-time per call: weight convert+transpose, BN stats, feats(t=0)
  wconv_k<<<dim3(1792 / 64, G4 / 64), 256, 0, stream>>>(W0, Wt0, 1792);
  wconv_k<<<dim3(2048 / 64, G4 / 64), 256, 0, stream>>>(W1, Wt1, 2048);
  bn_stats_k<<<QN_, 256, 0, stream>>>(x, bng, bnb, scale, shift);
  feats_k<<<N_, 256, 0, stream>>>(x, 0, scale, shift, QnV, QlV, fbufb);

  dim3 ggrid(G4 / 64, N_ / 64, 2);
  float* part1 = part + (size_t)N_ * G4;
  for (int t = 0; t < T_; ++t) {
    // layer 0: A = [h0 | feats_t], K = 1024 + 768 = 1792
    mfma_gemm_k<<<ggrid, 256, 0, stream>>>(h0b, H_, fbufb, FDIM, Wt0, 1792, 896, part);
    cell_k<<<N_, 256, 0, stream>>>(part, part1, b0, h0b, c0, lng, lnb,
                                   nullptr, nullptr, nullptr, t, 0,
                                   nullptr, nullptr, nullptr, nullptr, nullptr, nullptr, -1);
    // layer 1: A = [h1 | h0_new], K = 2048; fuse feats build for t+1
    mfma_gemm_k<<<ggrid, 256, 0, stream>>>(h1b, H_, h0b, H_, Wt1, 2048, 1024, part);
    cell_k<<<N_, 256, 0, stream>>>(part, part1, b1, h1b, c1, lng + 4 * H_, lnb + 4 * H_,
                                   fcW, fcb, out, t, 1,
                                   x, scale, shift, QnV, QlV, fbufb,
                                   (t + 1 < T_) ? t + 1 : -1);
  }
}